// Round 1
// baseline (2308.002 us; speedup 1.0000x reference)
//
#include <hip/hip_runtime.h>
#include <hip/hip_bf16.h>

constexpr int D = 256;   // dim_h
constexpr int PG = 1024; // nodes per graph

// ---------------------------------------------------------------------------
// Edge aggregation: z[dst] += relu(x[src] + edge_attr)   (z pre-initialized to x)
// one wave per edge; lane handles 4 consecutive dims
// ---------------------------------------------------------------------------
__global__ __launch_bounds__(256) void edge_aggr(
    const float* __restrict__ x, const float* __restrict__ ea,
    const int* __restrict__ src, const int* __restrict__ dst,
    float* __restrict__ z, int E)
{
    int gid = blockIdx.x * 256 + threadIdx.x;
    int e = gid >> 6;
    if (e >= E) return;
    int c = (gid & 63) << 2;
    int s = src[e], d = dst[e];
    float4 xa = *(const float4*)(x + (size_t)s * D + c);
    float4 av = *(const float4*)(ea + (size_t)e * D + c);
    float* zp = z + (size_t)d * D + c;
    atomicAdd(zp + 0, fmaxf(xa.x + av.x, 0.f));
    atomicAdd(zp + 1, fmaxf(xa.y + av.y, 0.f));
    atomicAdd(zp + 2, fmaxf(xa.z + av.z, 0.f));
    atomicAdd(zp + 3, fmaxf(xa.w + av.w, 0.f));
}

// ---------------------------------------------------------------------------
// Generic f32 GEMM: Y = act(X @ W^T + bias) (+ addsrc)
// X:[R,K], W:[M,K] row-major, Y:[R,M].  Tile 128x64, thread 8x4.
// ---------------------------------------------------------------------------
template<bool RELU, bool ADD>
__global__ __launch_bounds__(256) void gemm_xwt(
    const float* __restrict__ X, const float* __restrict__ W,
    const float* __restrict__ bias, const float* __restrict__ addsrc,
    float* __restrict__ Y, int K, int M)
{
    __shared__ float As[16][136];  // [k][row], padded: 136*4B = 16B-aligned rows
    __shared__ float Ws[16][72];   // [k][col]
    const int r0 = blockIdx.y * 128;
    const int c0 = blockIdx.x * 64;
    const int t  = threadIdx.x;
    const int ty = t >> 4, tx = t & 15;
    const int srow = t >> 2, skq = t & 3;
    float acc[8][4] = {};

    for (int k0 = 0; k0 < K; k0 += 16) {
        __syncthreads();
        {
            float4 va = *(const float4*)(X + (size_t)(r0 + srow) * K + k0 + skq * 4);
            float4 vb = *(const float4*)(X + (size_t)(r0 + 64 + srow) * K + k0 + skq * 4);
            float4 vw = *(const float4*)(W + (size_t)(c0 + srow) * K + k0 + skq * 4);
            As[skq*4+0][srow] = va.x; As[skq*4+1][srow] = va.y;
            As[skq*4+2][srow] = va.z; As[skq*4+3][srow] = va.w;
            As[skq*4+0][64+srow] = vb.x; As[skq*4+1][64+srow] = vb.y;
            As[skq*4+2][64+srow] = vb.z; As[skq*4+3][64+srow] = vb.w;
            Ws[skq*4+0][srow] = vw.x; Ws[skq*4+1][srow] = vw.y;
            Ws[skq*4+2][srow] = vw.z; Ws[skq*4+3][srow] = vw.w;
        }
        __syncthreads();
        #pragma unroll
        for (int k = 0; k < 16; ++k) {
            float4 a0 = *(const float4*)&As[k][ty*8];
            float4 a1 = *(const float4*)&As[k][ty*8+4];
            float4 b0 = *(const float4*)&Ws[k][tx*4];
            float a[8] = {a0.x,a0.y,a0.z,a0.w,a1.x,a1.y,a1.z,a1.w};
            float bb[4] = {b0.x,b0.y,b0.z,b0.w};
            #pragma unroll
            for (int i = 0; i < 8; ++i)
                #pragma unroll
                for (int j = 0; j < 4; ++j)
                    acc[i][j] = fmaf(a[i], bb[j], acc[i][j]);
        }
    }

    float4 bv = *(const float4*)(bias + c0 + tx*4);
    float bsc[4] = {bv.x, bv.y, bv.z, bv.w};
    #pragma unroll
    for (int i = 0; i < 8; ++i) {
        size_t off = (size_t)(r0 + ty*8 + i) * M + c0 + tx*4;
        float v0 = acc[i][0] + bsc[0], v1 = acc[i][1] + bsc[1];
        float v2 = acc[i][2] + bsc[2], v3 = acc[i][3] + bsc[3];
        if (RELU) {
            v0 = fmaxf(v0, 0.f); v1 = fmaxf(v1, 0.f);
            v2 = fmaxf(v2, 0.f); v3 = fmaxf(v3, 0.f);
        }
        if (ADD) {
            float4 ad = *(const float4*)(addsrc + off);
            v0 += ad.x; v1 += ad.y; v2 += ad.z; v3 += ad.w;
        }
        float4 r; r.x = v0; r.y = v1; r.z = v2; r.w = v3;
        *(float4*)(Y + off) = r;
    }
}

// ---------------------------------------------------------------------------
// Dense per-graph MHA. grid = (N/P)*H*2 blocks; block = 256 thr (4 waves).
// Each lane owns 2 q-rows (q,o in VGPRs); K/V tiles in LDS read as broadcast.
// Scores are O(1) => softmax without max subtraction is safe in f32.
// ---------------------------------------------------------------------------
__global__ __launch_bounds__(256) void attn_kernel(
    const float* __restrict__ QKV, float* __restrict__ O)
{
    const int bh = blockIdx.x >> 1, half = blockIdx.x & 1;
    const int b = bh >> 3, h = bh & 7;
    const int t = threadIdx.x, w = t >> 6, l = t & 63;
    const int qr1 = half * 512 + w * 128 + l;
    const int qr2 = qr1 + 64;
    const float rscale = 0.17677669529663687f;  // 1/sqrt(32)
    const size_t gb = (size_t)b * PG * 768;

    float q1[32], q2[32], o1[32], o2[32];
    {
        const float* Q1 = QKV + gb + (size_t)qr1 * 768 + h * 32;
        const float* Q2 = QKV + gb + (size_t)qr2 * 768 + h * 32;
        #pragma unroll
        for (int d4 = 0; d4 < 8; ++d4) {
            float4 a = *(const float4*)(Q1 + d4*4);
            float4 c = *(const float4*)(Q2 + d4*4);
            q1[d4*4+0] = a.x * rscale; q1[d4*4+1] = a.y * rscale;
            q1[d4*4+2] = a.z * rscale; q1[d4*4+3] = a.w * rscale;
            q2[d4*4+0] = c.x * rscale; q2[d4*4+1] = c.y * rscale;
            q2[d4*4+2] = c.z * rscale; q2[d4*4+3] = c.w * rscale;
            o1[d4*4+0] = 0.f; o1[d4*4+1] = 0.f; o1[d4*4+2] = 0.f; o1[d4*4+3] = 0.f;
            o2[d4*4+0] = 0.f; o2[d4*4+1] = 0.f; o2[d4*4+2] = 0.f; o2[d4*4+3] = 0.f;
        }
    }

    __shared__ float Ks[64][32];
    __shared__ float Vs[64][32];
    float l1 = 0.f, l2 = 0.f;
    const int skr = t >> 2, skq = t & 3;

    for (int kt = 0; kt < 16; ++kt) {
        __syncthreads();
        const float* Kr = QKV + gb + (size_t)(kt*64 + skr) * 768 + 256 + h*32 + skq*8;
        const float* Vr = QKV + gb + (size_t)(kt*64 + skr) * 768 + 512 + h*32 + skq*8;
        *(float4*)&Ks[skr][skq*8]     = *(const float4*)(Kr);
        *(float4*)&Ks[skr][skq*8 + 4] = *(const float4*)(Kr + 4);
        *(float4*)&Vs[skr][skq*8]     = *(const float4*)(Vr);
        *(float4*)&Vs[skr][skq*8 + 4] = *(const float4*)(Vr + 4);
        __syncthreads();

        for (int j = 0; j < 64; ++j) {
            float s1 = 0.f, s2 = 0.f;
            const float4* kj = (const float4*)&Ks[j][0];
            #pragma unroll
            for (int d4 = 0; d4 < 8; ++d4) {
                float4 kv = kj[d4];
                s1 = fmaf(q1[d4*4+0], kv.x, s1); s1 = fmaf(q1[d4*4+1], kv.y, s1);
                s1 = fmaf(q1[d4*4+2], kv.z, s1); s1 = fmaf(q1[d4*4+3], kv.w, s1);
                s2 = fmaf(q2[d4*4+0], kv.x, s2); s2 = fmaf(q2[d4*4+1], kv.y, s2);
                s2 = fmaf(q2[d4*4+2], kv.z, s2); s2 = fmaf(q2[d4*4+3], kv.w, s2);
            }
            float p1 = __expf(s1), p2 = __expf(s2);
            l1 += p1; l2 += p2;
            const float4* vj = (const float4*)&Vs[j][0];
            #pragma unroll
            for (int d4 = 0; d4 < 8; ++d4) {
                float4 vv = vj[d4];
                o1[d4*4+0] = fmaf(p1, vv.x, o1[d4*4+0]);
                o1[d4*4+1] = fmaf(p1, vv.y, o1[d4*4+1]);
                o1[d4*4+2] = fmaf(p1, vv.z, o1[d4*4+2]);
                o1[d4*4+3] = fmaf(p1, vv.w, o1[d4*4+3]);
                o2[d4*4+0] = fmaf(p2, vv.x, o2[d4*4+0]);
                o2[d4*4+1] = fmaf(p2, vv.y, o2[d4*4+1]);
                o2[d4*4+2] = fmaf(p2, vv.z, o2[d4*4+2]);
                o2[d4*4+3] = fmaf(p2, vv.w, o2[d4*4+3]);
            }
        }
    }

    float i1 = 1.f / l1, i2 = 1.f / l2;
    float* O1 = O + ((size_t)b * PG + qr1) * D + h * 32;
    float* O2 = O + ((size_t)b * PG + qr2) * D + h * 32;
    #pragma unroll
    for (int d4 = 0; d4 < 8; ++d4) {
        float4 r1, r2;
        r1.x = o1[d4*4+0]*i1; r1.y = o1[d4*4+1]*i1; r1.z = o1[d4*4+2]*i1; r1.w = o1[d4*4+3]*i1;
        r2.x = o2[d4*4+0]*i2; r2.y = o2[d4*4+1]*i2; r2.z = o2[d4*4+2]*i2; r2.w = o2[d4*4+3]*i2;
        *(float4*)(O1 + d4*4) = r1;
        *(float4*)(O2 + d4*4) = r2;
    }
}

// ---------------------------------------------------------------------------
// BatchNorm stats: per-column sum / sumsq partials, atomic into st[0:D], st[D:2D]
// ---------------------------------------------------------------------------
__global__ __launch_bounds__(256) void bn_stats(
    const float* __restrict__ X, float* __restrict__ st)
{
    const int c = threadIdx.x;
    const size_t r0 = (size_t)blockIdx.x * 64;
    float s = 0.f, q = 0.f;
    for (int r = 0; r < 64; ++r) {
        float v = X[(r0 + r) * D + c];
        s += v; q = fmaf(v, v, q);
    }
    atomicAdd(&st[c], s);
    atomicAdd(&st[D + c], q);
}

// ---------------------------------------------------------------------------
// H = BN(A; gl,bl,st[0:2D]) + BN(Bp; ga,ba,st[2D:4D])
// ---------------------------------------------------------------------------
__global__ __launch_bounds__(256) void bn_combine(
    const float* __restrict__ A, const float* __restrict__ Bp,
    const float* __restrict__ gl, const float* __restrict__ bl,
    const float* __restrict__ ga, const float* __restrict__ ba,
    const float* __restrict__ st, float* __restrict__ H, int n)
{
    const float invN = 1.0f / (float)n;
    size_t i = (size_t)blockIdx.x * 256 + threadIdx.x;
    int c0 = (int)((i & 63) << 2);
    float4 a = ((const float4*)A)[i];
    float4 bb = ((const float4*)Bp)[i];
    float av[4] = {a.x, a.y, a.z, a.w}, bv[4] = {bb.x, bb.y, bb.z, bb.w}, r[4];
    #pragma unroll
    for (int j = 0; j < 4; ++j) {
        int c = c0 + j;
        float m1 = st[c] * invN;
        float v1 = fmaxf(st[D + c] * invN - m1 * m1, 0.f);
        float m2 = st[2*D + c] * invN;
        float v2 = fmaxf(st[3*D + c] * invN - m2 * m2, 0.f);
        float y1 = gl[c] * (av[j] - m1) * rsqrtf(v1 + 1e-5f) + bl[c];
        float y2 = ga[c] * (bv[j] - m2) * rsqrtf(v2 + 1e-5f) + ba[c];
        r[j] = y1 + y2;
    }
    float4 o; o.x = r[0]; o.y = r[1]; o.z = r[2]; o.w = r[3];
    ((float4*)H)[i] = o;
}

// ---------------------------------------------------------------------------
// out = BN(X; g,b,st)
// ---------------------------------------------------------------------------
__global__ __launch_bounds__(256) void bn_apply(
    const float* __restrict__ X, const float* __restrict__ g,
    const float* __restrict__ bb, const float* __restrict__ st,
    float* __restrict__ out, int n)
{
    const float invN = 1.0f / (float)n;
    size_t i = (size_t)blockIdx.x * 256 + threadIdx.x;
    int c0 = (int)((i & 63) << 2);
    float4 xv = ((const float4*)X)[i];
    float x4[4] = {xv.x, xv.y, xv.z, xv.w}, r[4];
    #pragma unroll
    for (int j = 0; j < 4; ++j) {
        int c = c0 + j;
        float m = st[c] * invN;
        float v = fmaxf(st[D + c] * invN - m * m, 0.f);
        r[j] = g[c] * (x4[j] - m) * rsqrtf(v + 1e-5f) + bb[c];
    }
    float4 o; o.x = r[0]; o.y = r[1]; o.z = r[2]; o.w = r[3];
    ((float4*)out)[i] = o;
}

// ---------------------------------------------------------------------------
extern "C" void kernel_launch(void* const* d_in, const int* in_sizes, int n_in,
                              void* d_out, int out_size, void* d_ws, size_t ws_size,
                              hipStream_t stream)
{
    const float* x    = (const float*)d_in[0];
    const int*   ei   = (const int*)d_in[1];
    const float* ea   = (const float*)d_in[2];
    const float* gw1  = (const float*)d_in[3];
    const float* gb1  = (const float*)d_in[4];
    const float* gw2  = (const float*)d_in[5];
    const float* gb2  = (const float*)d_in[6];
    const float* inw  = (const float*)d_in[7];
    const float* inb  = (const float*)d_in[8];
    const float* outw = (const float*)d_in[9];
    const float* outb = (const float*)d_in[10];
    const float* g1l  = (const float*)d_in[11];
    const float* b1l  = (const float*)d_in[12];
    const float* g1a  = (const float*)d_in[13];
    const float* b1a  = (const float*)d_in[14];
    const float* fw1  = (const float*)d_in[15];
    const float* fb1  = (const float*)d_in[16];
    const float* fw2  = (const float*)d_in[17];
    const float* fb2  = (const float*)d_in[18];
    const float* g2   = (const float*)d_in[19];
    const float* b2   = (const float*)d_in[20];
    float* out = (float*)d_out;

    const int N = in_sizes[0] / D;   // 32768
    const int E = in_sizes[1] / 2;   // 262144
    const size_t ND = (size_t)N * D;

    float* U0 = (float*)d_ws;        // HLpre -> OUTpre
    float* U1 = U0 + ND;             // T1 -> QKV(lo) -> HApre
    float* U2 = U0 + 2 * ND;         //        QKV(mid) -> Hc
    float* U3 = U0 + 3 * ND;         //        QKV(hi) -> FFH(lo)
    float* U4 = U0 + 4 * ND;         // Z -> O -> FFH(hi)
    float* st = U0 + 5 * ND;         // 1536 floats of BN stats

    const int GR = N / 128;          // GEMM row-blocks

    // ---- local branch: z = x + sum_e relu(x[src]+ea) ----
    hipMemcpyAsync(U4, x, ND * sizeof(float), hipMemcpyDeviceToDevice, stream);
    hipMemsetAsync(st, 0, 1536 * sizeof(float), stream);
    edge_aggr<<<(E * 64) / 256, 256, 0, stream>>>(x, ea, ei, ei + E, U4, E);
    gemm_xwt<true , false><<<dim3(D/64, GR), 256, 0, stream>>>(U4, gw1, gb1, nullptr, U1, D, D);
    gemm_xwt<false, true ><<<dim3(D/64, GR), 256, 0, stream>>>(U1, gw2, gb2, x, U0, D, D);

    // ---- global branch: QKV -> attention -> out-proj ----
    gemm_xwt<false, false><<<dim3(768/64, GR), 256, 0, stream>>>(x, inw, inb, nullptr, U1, D, 768);
    attn_kernel<<<(N / PG) * 16, 256, 0, stream>>>(U1, U4);
    gemm_xwt<false, true ><<<dim3(D/64, GR), 256, 0, stream>>>(U4, outw, outb, x, U1, D, D);

    // ---- BN both branches, combine ----
    bn_stats<<<N/64, 256, 0, stream>>>(U0, st);
    bn_stats<<<N/64, 256, 0, stream>>>(U1, st + 512);
    bn_combine<<<(unsigned)(ND / 4 / 256), 256, 0, stream>>>(U0, U1, g1l, b1l, g1a, b1a, st, U2, N);

    // ---- FF + final BN ----
    gemm_xwt<true , false><<<dim3(512/64, GR), 256, 0, stream>>>(U2, fw1, fb1, nullptr, U3, D, 512);
    gemm_xwt<false, true ><<<dim3(D/64, GR), 256, 0, stream>>>(U3, fw2, fb2, U2, U0, 512, D);
    bn_stats<<<N/64, 256, 0, stream>>>(U0, st + 1024);
    bn_apply<<<(unsigned)(ND / 4 / 256), 256, 0, stream>>>(U0, g2, b2, st + 1024, out, N);
}

// Round 2
// 1541.121 us; speedup vs baseline: 1.4976x; 1.4976x over previous
//
#include <hip/hip_runtime.h>
#include <hip/hip_bf16.h>

constexpr int D = 256;   // dim_h
constexpr int PG = 1024; // nodes per graph

// ===========================================================================
// CSR build: histogram -> 2-level exclusive scan -> scatter
// ===========================================================================
__global__ __launch_bounds__(256) void hist_kernel(
    const int* __restrict__ dst, int* __restrict__ cnt, int E)
{
    int e = blockIdx.x * 256 + threadIdx.x;
    if (e < E) atomicAdd(&cnt[dst[e]], 1);
}

__global__ __launch_bounds__(256) void scan_block(
    const int* __restrict__ cnt, int* __restrict__ excl, int* __restrict__ bsum)
{
    __shared__ int sm[256];
    const int t = threadIdx.x;
    const int i = blockIdx.x * 256 + t;
    int v = cnt[i];
    sm[t] = v;
    __syncthreads();
    #pragma unroll
    for (int o = 1; o < 256; o <<= 1) {
        int u = (t >= o) ? sm[t - o] : 0;
        __syncthreads();
        sm[t] += u;
        __syncthreads();
    }
    excl[i] = sm[t] - v;
    if (t == 255) bsum[blockIdx.x] = sm[255];
}

__global__ __launch_bounds__(128) void scan_bsum(int* __restrict__ bsum)
{
    __shared__ int sm[128];
    const int t = threadIdx.x;
    int v = bsum[t];
    sm[t] = v;
    __syncthreads();
    #pragma unroll
    for (int o = 1; o < 128; o <<= 1) {
        int u = (t >= o) ? sm[t - o] : 0;
        __syncthreads();
        sm[t] += u;
        __syncthreads();
    }
    bsum[t] = sm[t] - v;
}

__global__ __launch_bounds__(256) void scan_add(
    const int* __restrict__ excl, const int* __restrict__ bsum,
    int* __restrict__ rowptr, int* __restrict__ ofs)
{
    int i = blockIdx.x * 256 + threadIdx.x;
    int r = excl[i] + bsum[blockIdx.x];
    rowptr[i] = r;
    ofs[i] = r;
}

__global__ __launch_bounds__(256) void scatter_kernel(
    const int* __restrict__ src, const int* __restrict__ dst,
    int* __restrict__ ofs, int* __restrict__ eord, int* __restrict__ esrc, int E)
{
    int e = blockIdx.x * 256 + threadIdx.x;
    if (e >= E) return;
    int d = dst[e];
    int pos = atomicAdd(&ofs[d], 1);
    eord[pos] = e;
    esrc[pos] = src[e];
}

// ===========================================================================
// CSR aggregation: one wave per dst node. z[n] = x[n] + sum_e relu(x[src]+ea)
// ===========================================================================
__global__ __launch_bounds__(256) void csr_aggr(
    const float* __restrict__ x, const float* __restrict__ ea,
    const int* __restrict__ rowptr, const int* __restrict__ cnt,
    const int* __restrict__ eord, const int* __restrict__ esrc,
    float* __restrict__ z)
{
    int gid = blockIdx.x * 256 + threadIdx.x;
    int node = gid >> 6;
    int c = (gid & 63) << 2;
    int start = rowptr[node];
    int deg = cnt[node];
    float4 acc = *(const float4*)(x + (size_t)node * D + c);
    for (int i = 0; i < deg; ++i) {
        int e = eord[start + i];
        int s = esrc[start + i];
        float4 xa = *(const float4*)(x + (size_t)s * D + c);
        float4 av = *(const float4*)(ea + (size_t)e * D + c);
        acc.x += fmaxf(xa.x + av.x, 0.f);
        acc.y += fmaxf(xa.y + av.y, 0.f);
        acc.z += fmaxf(xa.z + av.z, 0.f);
        acc.w += fmaxf(xa.w + av.w, 0.f);
    }
    *(float4*)(z + (size_t)node * D + c) = acc;
}

// ---------------------------------------------------------------------------
// Generic f32 GEMM: Y = act(X @ W^T + bias) (+ addsrc)
// X:[R,K], W:[M,K] row-major, Y:[R,M].  Tile 128x64, thread 8x4.
// ---------------------------------------------------------------------------
template<bool RELU, bool ADD>
__global__ __launch_bounds__(256) void gemm_xwt(
    const float* __restrict__ X, const float* __restrict__ W,
    const float* __restrict__ bias, const float* __restrict__ addsrc,
    float* __restrict__ Y, int K, int M)
{
    __shared__ float As[16][136];
    __shared__ float Ws[16][72];
    const int r0 = blockIdx.y * 128;
    const int c0 = blockIdx.x * 64;
    const int t  = threadIdx.x;
    const int ty = t >> 4, tx = t & 15;
    const int srow = t >> 2, skq = t & 3;
    float acc[8][4] = {};

    for (int k0 = 0; k0 < K; k0 += 16) {
        __syncthreads();
        {
            float4 va = *(const float4*)(X + (size_t)(r0 + srow) * K + k0 + skq * 4);
            float4 vb = *(const float4*)(X + (size_t)(r0 + 64 + srow) * K + k0 + skq * 4);
            float4 vw = *(const float4*)(W + (size_t)(c0 + srow) * K + k0 + skq * 4);
            As[skq*4+0][srow] = va.x; As[skq*4+1][srow] = va.y;
            As[skq*4+2][srow] = va.z; As[skq*4+3][srow] = va.w;
            As[skq*4+0][64+srow] = vb.x; As[skq*4+1][64+srow] = vb.y;
            As[skq*4+2][64+srow] = vb.z; As[skq*4+3][64+srow] = vb.w;
            Ws[skq*4+0][srow] = vw.x; Ws[skq*4+1][srow] = vw.y;
            Ws[skq*4+2][srow] = vw.z; Ws[skq*4+3][srow] = vw.w;
        }
        __syncthreads();
        #pragma unroll
        for (int k = 0; k < 16; ++k) {
            float4 a0 = *(const float4*)&As[k][ty*8];
            float4 a1 = *(const float4*)&As[k][ty*8+4];
            float4 b0 = *(const float4*)&Ws[k][tx*4];
            float a[8] = {a0.x,a0.y,a0.z,a0.w,a1.x,a1.y,a1.z,a1.w};
            float bb[4] = {b0.x,b0.y,b0.z,b0.w};
            #pragma unroll
            for (int i = 0; i < 8; ++i)
                #pragma unroll
                for (int j = 0; j < 4; ++j)
                    acc[i][j] = fmaf(a[i], bb[j], acc[i][j]);
        }
    }

    float4 bv = *(const float4*)(bias + c0 + tx*4);
    float bsc[4] = {bv.x, bv.y, bv.z, bv.w};
    #pragma unroll
    for (int i = 0; i < 8; ++i) {
        size_t off = (size_t)(r0 + ty*8 + i) * M + c0 + tx*4;
        float v0 = acc[i][0] + bsc[0], v1 = acc[i][1] + bsc[1];
        float v2 = acc[i][2] + bsc[2], v3 = acc[i][3] + bsc[3];
        if (RELU) {
            v0 = fmaxf(v0, 0.f); v1 = fmaxf(v1, 0.f);
            v2 = fmaxf(v2, 0.f); v3 = fmaxf(v3, 0.f);
        }
        if (ADD) {
            float4 ad = *(const float4*)(addsrc + off);
            v0 += ad.x; v1 += ad.y; v2 += ad.z; v3 += ad.w;
        }
        float4 r; r.x = v0; r.y = v1; r.z = v2; r.w = v3;
        *(float4*)(Y + off) = r;
    }
}

// ---------------------------------------------------------------------------
// Dense per-graph MHA. grid = (N/P)*H*2 blocks; block = 256 thr (4 waves).
// ---------------------------------------------------------------------------
__global__ __launch_bounds__(256) void attn_kernel(
    const float* __restrict__ QKV, float* __restrict__ O)
{
    const int bh = blockIdx.x >> 1, half = blockIdx.x & 1;
    const int b = bh >> 3, h = bh & 7;
    const int t = threadIdx.x, w = t >> 6, l = t & 63;
    const int qr1 = half * 512 + w * 128 + l;
    const int qr2 = qr1 + 64;
    const float rscale = 0.17677669529663687f;  // 1/sqrt(32)
    const size_t gb = (size_t)b * PG * 768;

    float q1[32], q2[32], o1[32], o2[32];
    {
        const float* Q1 = QKV + gb + (size_t)qr1 * 768 + h * 32;
        const float* Q2 = QKV + gb + (size_t)qr2 * 768 + h * 32;
        #pragma unroll
        for (int d4 = 0; d4 < 8; ++d4) {
            float4 a = *(const float4*)(Q1 + d4*4);
            float4 c = *(const float4*)(Q2 + d4*4);
            q1[d4*4+0] = a.x * rscale; q1[d4*4+1] = a.y * rscale;
            q1[d4*4+2] = a.z * rscale; q1[d4*4+3] = a.w * rscale;
            q2[d4*4+0] = c.x * rscale; q2[d4*4+1] = c.y * rscale;
            q2[d4*4+2] = c.z * rscale; q2[d4*4+3] = c.w * rscale;
            o1[d4*4+0] = 0.f; o1[d4*4+1] = 0.f; o1[d4*4+2] = 0.f; o1[d4*4+3] = 0.f;
            o2[d4*4+0] = 0.f; o2[d4*4+1] = 0.f; o2[d4*4+2] = 0.f; o2[d4*4+3] = 0.f;
        }
    }

    __shared__ float Ks[64][32];
    __shared__ float Vs[64][32];
    float l1 = 0.f, l2 = 0.f;
    const int skr = t >> 2, skq = t & 3;

    for (int kt = 0; kt < 16; ++kt) {
        __syncthreads();
        const float* Kr = QKV + gb + (size_t)(kt*64 + skr) * 768 + 256 + h*32 + skq*8;
        const float* Vr = QKV + gb + (size_t)(kt*64 + skr) * 768 + 512 + h*32 + skq*8;
        *(float4*)&Ks[skr][skq*8]     = *(const float4*)(Kr);
        *(float4*)&Ks[skr][skq*8 + 4] = *(const float4*)(Kr + 4);
        *(float4*)&Vs[skr][skq*8]     = *(const float4*)(Vr);
        *(float4*)&Vs[skr][skq*8 + 4] = *(const float4*)(Vr + 4);
        __syncthreads();

        for (int j = 0; j < 64; ++j) {
            float s1 = 0.f, s2 = 0.f;
            const float4* kj = (const float4*)&Ks[j][0];
            #pragma unroll
            for (int d4 = 0; d4 < 8; ++d4) {
                float4 kv = kj[d4];
                s1 = fmaf(q1[d4*4+0], kv.x, s1); s1 = fmaf(q1[d4*4+1], kv.y, s1);
                s1 = fmaf(q1[d4*4+2], kv.z, s1); s1 = fmaf(q1[d4*4+3], kv.w, s1);
                s2 = fmaf(q2[d4*4+0], kv.x, s2); s2 = fmaf(q2[d4*4+1], kv.y, s2);
                s2 = fmaf(q2[d4*4+2], kv.z, s2); s2 = fmaf(q2[d4*4+3], kv.w, s2);
            }
            float p1 = __expf(s1), p2 = __expf(s2);
            l1 += p1; l2 += p2;
            const float4* vj = (const float4*)&Vs[j][0];
            #pragma unroll
            for (int d4 = 0; d4 < 8; ++d4) {
                float4 vv = vj[d4];
                o1[d4*4+0] = fmaf(p1, vv.x, o1[d4*4+0]);
                o1[d4*4+1] = fmaf(p1, vv.y, o1[d4*4+1]);
                o1[d4*4+2] = fmaf(p1, vv.z, o1[d4*4+2]);
                o1[d4*4+3] = fmaf(p1, vv.w, o1[d4*4+3]);
                o2[d4*4+0] = fmaf(p2, vv.x, o2[d4*4+0]);
                o2[d4*4+1] = fmaf(p2, vv.y, o2[d4*4+1]);
                o2[d4*4+2] = fmaf(p2, vv.z, o2[d4*4+2]);
                o2[d4*4+3] = fmaf(p2, vv.w, o2[d4*4+3]);
            }
        }
    }

    float i1 = 1.f / l1, i2 = 1.f / l2;
    float* O1 = O + ((size_t)b * PG + qr1) * D + h * 32;
    float* O2 = O + ((size_t)b * PG + qr2) * D + h * 32;
    #pragma unroll
    for (int d4 = 0; d4 < 8; ++d4) {
        float4 r1, r2;
        r1.x = o1[d4*4+0]*i1; r1.y = o1[d4*4+1]*i1; r1.z = o1[d4*4+2]*i1; r1.w = o1[d4*4+3]*i1;
        r2.x = o2[d4*4+0]*i2; r2.y = o2[d4*4+1]*i2; r2.z = o2[d4*4+2]*i2; r2.w = o2[d4*4+3]*i2;
        *(float4*)(O1 + d4*4) = r1;
        *(float4*)(O2 + d4*4) = r2;
    }
}

// ---------------------------------------------------------------------------
// BatchNorm stats: per-column sum / sumsq partials
// ---------------------------------------------------------------------------
__global__ __launch_bounds__(256) void bn_stats(
    const float* __restrict__ X, float* __restrict__ st)
{
    const int c = threadIdx.x;
    const size_t r0 = (size_t)blockIdx.x * 64;
    float s = 0.f, q = 0.f;
    for (int r = 0; r < 64; ++r) {
        float v = X[(r0 + r) * D + c];
        s += v; q = fmaf(v, v, q);
    }
    atomicAdd(&st[c], s);
    atomicAdd(&st[D + c], q);
}

__global__ __launch_bounds__(256) void bn_combine(
    const float* __restrict__ A, const float* __restrict__ Bp,
    const float* __restrict__ gl, const float* __restrict__ bl,
    const float* __restrict__ ga, const float* __restrict__ ba,
    const float* __restrict__ st, float* __restrict__ H, int n)
{
    const float invN = 1.0f / (float)n;
    size_t i = (size_t)blockIdx.x * 256 + threadIdx.x;
    int c0 = (int)((i & 63) << 2);
    float4 a = ((const float4*)A)[i];
    float4 bb = ((const float4*)Bp)[i];
    float av[4] = {a.x, a.y, a.z, a.w}, bv[4] = {bb.x, bb.y, bb.z, bb.w}, r[4];
    #pragma unroll
    for (int j = 0; j < 4; ++j) {
        int c = c0 + j;
        float m1 = st[c] * invN;
        float v1 = fmaxf(st[D + c] * invN - m1 * m1, 0.f);
        float m2 = st[2*D + c] * invN;
        float v2 = fmaxf(st[3*D + c] * invN - m2 * m2, 0.f);
        float y1 = gl[c] * (av[j] - m1) * rsqrtf(v1 + 1e-5f) + bl[c];
        float y2 = ga[c] * (bv[j] - m2) * rsqrtf(v2 + 1e-5f) + ba[c];
        r[j] = y1 + y2;
    }
    float4 o; o.x = r[0]; o.y = r[1]; o.z = r[2]; o.w = r[3];
    ((float4*)H)[i] = o;
}

__global__ __launch_bounds__(256) void bn_apply(
    const float* __restrict__ X, const float* __restrict__ g,
    const float* __restrict__ bb, const float* __restrict__ st,
    float* __restrict__ out, int n)
{
    const float invN = 1.0f / (float)n;
    size_t i = (size_t)blockIdx.x * 256 + threadIdx.x;
    int c0 = (int)((i & 63) << 2);
    float4 xv = ((const float4*)X)[i];
    float x4[4] = {xv.x, xv.y, xv.z, xv.w}, r[4];
    #pragma unroll
    for (int j = 0; j < 4; ++j) {
        int c = c0 + j;
        float m = st[c] * invN;
        float v = fmaxf(st[D + c] * invN - m * m, 0.f);
        r[j] = g[c] * (x4[j] - m) * rsqrtf(v + 1e-5f) + bb[c];
    }
    float4 o; o.x = r[0]; o.y = r[1]; o.z = r[2]; o.w = r[3];
    ((float4*)out)[i] = o;
}

// ---------------------------------------------------------------------------
extern "C" void kernel_launch(void* const* d_in, const int* in_sizes, int n_in,
                              void* d_out, int out_size, void* d_ws, size_t ws_size,
                              hipStream_t stream)
{
    const float* x    = (const float*)d_in[0];
    const int*   ei   = (const int*)d_in[1];
    const float* ea   = (const float*)d_in[2];
    const float* gw1  = (const float*)d_in[3];
    const float* gb1  = (const float*)d_in[4];
    const float* gw2  = (const float*)d_in[5];
    const float* gb2  = (const float*)d_in[6];
    const float* inw  = (const float*)d_in[7];
    const float* inb  = (const float*)d_in[8];
    const float* outw = (const float*)d_in[9];
    const float* outb = (const float*)d_in[10];
    const float* g1l  = (const float*)d_in[11];
    const float* b1l  = (const float*)d_in[12];
    const float* g1a  = (const float*)d_in[13];
    const float* b1a  = (const float*)d_in[14];
    const float* fw1  = (const float*)d_in[15];
    const float* fb1  = (const float*)d_in[16];
    const float* fw2  = (const float*)d_in[17];
    const float* fb2  = (const float*)d_in[18];
    const float* g2   = (const float*)d_in[19];
    const float* b2   = (const float*)d_in[20];
    float* out = (float*)d_out;

    const int N = in_sizes[0] / D;   // 32768
    const int E = in_sizes[1] / 2;   // 262144
    const size_t ND = (size_t)N * D;

    float* U0 = (float*)d_ws;        // HLpre -> OUTpre
    float* U1 = U0 + ND;             // T1 -> QKV -> HApre
    float* U2 = U0 + 2 * ND;
    float* U3 = U0 + 3 * ND;
    float* U4 = U0 + 4 * ND;         // Z -> O -> FFH(hi)
    float* st = U0 + 5 * ND;         // 1536 floats of BN stats

    // CSR scratch (ints) after stats
    int* cnt    = (int*)(st + 1536);
    int* excl   = cnt + N;
    int* rowptr = excl + N;
    int* ofs    = rowptr + N;
    int* bsum   = ofs + N;           // 128 used
    int* eord   = bsum + 256;
    int* esrc   = eord + E;

    const int GR = N / 128;          // GEMM row-blocks
    const int EB = (E + 255) / 256;

    // ---- CSR build ----
    hipMemsetAsync(cnt, 0, (size_t)N * sizeof(int), stream);
    hipMemsetAsync(st, 0, 1536 * sizeof(float), stream);
    hist_kernel<<<EB, 256, 0, stream>>>(ei + E, cnt, E);
    scan_block<<<N / 256, 256, 0, stream>>>(cnt, excl, bsum);
    scan_bsum<<<1, 128, 0, stream>>>(bsum);
    scan_add<<<N / 256, 256, 0, stream>>>(excl, bsum, rowptr, ofs);
    scatter_kernel<<<EB, 256, 0, stream>>>(ei, ei + E, ofs, eord, esrc, E);

    // ---- local branch: z = x + sum_e relu(x[src]+ea) ----
    csr_aggr<<<(N * 64) / 256, 256, 0, stream>>>(x, ea, rowptr, cnt, eord, esrc, U4);
    gemm_xwt<true , false><<<dim3(D/64, GR), 256, 0, stream>>>(U4, gw1, gb1, nullptr, U1, D, D);
    gemm_xwt<false, true ><<<dim3(D/64, GR), 256, 0, stream>>>(U1, gw2, gb2, x, U0, D, D);

    // ---- global branch: QKV -> attention -> out-proj ----
    gemm_xwt<false, false><<<dim3(768/64, GR), 256, 0, stream>>>(x, inw, inb, nullptr, U1, D, 768);
    attn_kernel<<<(N / PG) * 16, 256, 0, stream>>>(U1, U4);
    gemm_xwt<false, true ><<<dim3(D/64, GR), 256, 0, stream>>>(U4, outw, outb, x, U1, D, D);

    // ---- BN both branches, combine ----
    bn_stats<<<N/64, 256, 0, stream>>>(U0, st);
    bn_stats<<<N/64, 256, 0, stream>>>(U1, st + 512);
    bn_combine<<<(unsigned)(ND / 4 / 256), 256, 0, stream>>>(U0, U1, g1l, b1l, g1a, b1a, st, U2, N);

    // ---- FF + final BN ----
    gemm_xwt<true , false><<<dim3(512/64, GR), 256, 0, stream>>>(U2, fw1, fb1, nullptr, U3, D, 512);
    gemm_xwt<false, true ><<<dim3(D/64, GR), 256, 0, stream>>>(U3, fw2, fb2, U2, U0, 512, D);
    bn_stats<<<N/64, 256, 0, stream>>>(U0, st + 1024);
    bn_apply<<<(unsigned)(ND / 4 / 256), 256, 0, stream>>>(U0, g2, b2, st + 1024, out, N);
}

// Round 3
// 947.952 us; speedup vs baseline: 2.4347x; 1.6257x over previous
//
#include <hip/hip_runtime.h>
#include <hip/hip_bf16.h>

constexpr int D = 256;   // dim_h
constexpr int PG = 1024; // nodes per graph

typedef __attribute__((ext_vector_type(8))) short bf16x8;  // 8 bf16 in 4 VGPRs
typedef __attribute__((ext_vector_type(4))) float f32x4;

__device__ inline short f2bf(float f) {
    __hip_bfloat16 h = __float2bfloat16(f);
    return *reinterpret_cast<short*>(&h);
}

// ===========================================================================
// CSR build: histogram -> 2-level exclusive scan -> scatter
// ===========================================================================
__global__ __launch_bounds__(256) void hist_kernel(
    const int* __restrict__ dst, int* __restrict__ cnt, int E)
{
    int e = blockIdx.x * 256 + threadIdx.x;
    if (e < E) atomicAdd(&cnt[dst[e]], 1);
}

__global__ __launch_bounds__(256) void scan_block(
    const int* __restrict__ cnt, int* __restrict__ excl, int* __restrict__ bsum)
{
    __shared__ int sm[256];
    const int t = threadIdx.x;
    const int i = blockIdx.x * 256 + t;
    int v = cnt[i];
    sm[t] = v;
    __syncthreads();
    #pragma unroll
    for (int o = 1; o < 256; o <<= 1) {
        int u = (t >= o) ? sm[t - o] : 0;
        __syncthreads();
        sm[t] += u;
        __syncthreads();
    }
    excl[i] = sm[t] - v;
    if (t == 255) bsum[blockIdx.x] = sm[255];
}

__global__ __launch_bounds__(128) void scan_bsum(int* __restrict__ bsum)
{
    __shared__ int sm[128];
    const int t = threadIdx.x;
    int v = bsum[t];
    sm[t] = v;
    __syncthreads();
    #pragma unroll
    for (int o = 1; o < 128; o <<= 1) {
        int u = (t >= o) ? sm[t - o] : 0;
        __syncthreads();
        sm[t] += u;
        __syncthreads();
    }
    bsum[t] = sm[t] - v;
}

__global__ __launch_bounds__(256) void scan_add(
    const int* __restrict__ excl, const int* __restrict__ bsum,
    int* __restrict__ rowptr, int* __restrict__ ofs)
{
    int i = blockIdx.x * 256 + threadIdx.x;
    int r = excl[i] + bsum[blockIdx.x];
    rowptr[i] = r;
    ofs[i] = r;
}

__global__ __launch_bounds__(256) void scatter_kernel(
    const int* __restrict__ src, const int* __restrict__ dst,
    int* __restrict__ ofs, int* __restrict__ eord, int* __restrict__ esrc, int E)
{
    int e = blockIdx.x * 256 + threadIdx.x;
    if (e >= E) return;
    int d = dst[e];
    int pos = atomicAdd(&ofs[d], 1);
    eord[pos] = e;
    esrc[pos] = src[e];
}

// ===========================================================================
// CSR aggregation: one wave per dst node. z[n] = x[n] + sum_e relu(x[src]+ea)
// ===========================================================================
__global__ __launch_bounds__(256) void csr_aggr(
    const float* __restrict__ x, const float* __restrict__ ea,
    const int* __restrict__ rowptr, const int* __restrict__ cnt,
    const int* __restrict__ eord, const int* __restrict__ esrc,
    float* __restrict__ z)
{
    int gid = blockIdx.x * 256 + threadIdx.x;
    int node = gid >> 6;
    int c = (gid & 63) << 2;
    int start = rowptr[node];
    int deg = cnt[node];
    float4 acc = *(const float4*)(x + (size_t)node * D + c);
    for (int i = 0; i < deg; ++i) {
        int e = eord[start + i];
        int s = esrc[start + i];
        float4 xa = *(const float4*)(x + (size_t)s * D + c);
        float4 av = *(const float4*)(ea + (size_t)e * D + c);
        acc.x += fmaxf(xa.x + av.x, 0.f);
        acc.y += fmaxf(xa.y + av.y, 0.f);
        acc.z += fmaxf(xa.z + av.z, 0.f);
        acc.w += fmaxf(xa.w + av.w, 0.f);
    }
    *(float4*)(z + (size_t)node * D + c) = acc;
}

// ---------------------------------------------------------------------------
// Generic f32 GEMM: Y = act(X @ W^T + bias) (+ addsrc)
// ---------------------------------------------------------------------------
template<bool RELU, bool ADD>
__global__ __launch_bounds__(256) void gemm_xwt(
    const float* __restrict__ X, const float* __restrict__ W,
    const float* __restrict__ bias, const float* __restrict__ addsrc,
    float* __restrict__ Y, int K, int M)
{
    __shared__ float As[16][136];
    __shared__ float Ws[16][72];
    const int r0 = blockIdx.y * 128;
    const int c0 = blockIdx.x * 64;
    const int t  = threadIdx.x;
    const int ty = t >> 4, tx = t & 15;
    const int srow = t >> 2, skq = t & 3;
    float acc[8][4] = {};

    for (int k0 = 0; k0 < K; k0 += 16) {
        __syncthreads();
        {
            float4 va = *(const float4*)(X + (size_t)(r0 + srow) * K + k0 + skq * 4);
            float4 vb = *(const float4*)(X + (size_t)(r0 + 64 + srow) * K + k0 + skq * 4);
            float4 vw = *(const float4*)(W + (size_t)(c0 + srow) * K + k0 + skq * 4);
            As[skq*4+0][srow] = va.x; As[skq*4+1][srow] = va.y;
            As[skq*4+2][srow] = va.z; As[skq*4+3][srow] = va.w;
            As[skq*4+0][64+srow] = vb.x; As[skq*4+1][64+srow] = vb.y;
            As[skq*4+2][64+srow] = vb.z; As[skq*4+3][64+srow] = vb.w;
            Ws[skq*4+0][srow] = vw.x; Ws[skq*4+1][srow] = vw.y;
            Ws[skq*4+2][srow] = vw.z; Ws[skq*4+3][srow] = vw.w;
        }
        __syncthreads();
        #pragma unroll
        for (int k = 0; k < 16; ++k) {
            float4 a0 = *(const float4*)&As[k][ty*8];
            float4 a1 = *(const float4*)&As[k][ty*8+4];
            float4 b0 = *(const float4*)&Ws[k][tx*4];
            float a[8] = {a0.x,a0.y,a0.z,a0.w,a1.x,a1.y,a1.z,a1.w};
            float bb[4] = {b0.x,b0.y,b0.z,b0.w};
            #pragma unroll
            for (int i = 0; i < 8; ++i)
                #pragma unroll
                for (int j = 0; j < 4; ++j)
                    acc[i][j] = fmaf(a[i], bb[j], acc[i][j]);
        }
    }

    float4 bv = *(const float4*)(bias + c0 + tx*4);
    float bsc[4] = {bv.x, bv.y, bv.z, bv.w};
    #pragma unroll
    for (int i = 0; i < 8; ++i) {
        size_t off = (size_t)(r0 + ty*8 + i) * M + c0 + tx*4;
        float v0 = acc[i][0] + bsc[0], v1 = acc[i][1] + bsc[1];
        float v2 = acc[i][2] + bsc[2], v3 = acc[i][3] + bsc[3];
        if (RELU) {
            v0 = fmaxf(v0, 0.f); v1 = fmaxf(v1, 0.f);
            v2 = fmaxf(v2, 0.f); v3 = fmaxf(v3, 0.f);
        }
        if (ADD) {
            float4 ad = *(const float4*)(addsrc + off);
            v0 += ad.x; v1 += ad.y; v2 += ad.z; v3 += ad.w;
        }
        float4 r; r.x = v0; r.y = v1; r.z = v2; r.w = v3;
        *(float4*)(Y + off) = r;
    }
}

// ===========================================================================
// MFMA bf16 attention. Block = 4 waves = one (b,h), 128 q-rows.
// blockIdx.x = (qblk<<8) | (b*8+h)  -> same head's q-blocks share an XCD.
// Wave owns 32 q-rows (2 A-frags). Keys tiled by 64: K[64][32]->LDS(stride40),
// V^T[32][64]->LDS(stride72). Scores bounded => exp without max-tracking.
// P round-trips via per-wave LDS tile (stride 72) to fix the A-frag layout.
// ===========================================================================
__global__ __launch_bounds__(256) void attn_mfma(
    const float* __restrict__ QKV, float* __restrict__ O)
{
    const int bh = blockIdx.x & 255;
    const int qblk = blockIdx.x >> 8;
    const int b = bh >> 3, h = bh & 7;
    const int t = threadIdx.x, w = t >> 6, l = t & 63;
    const int lg = l >> 4, lm = l & 15;
    const size_t gb = (size_t)b * PG * 768;
    const int q0 = qblk * 128 + w * 32;
    const float rscale = 0.17677669529663687f;  // 1/sqrt(32)

    __shared__ __align__(16) short Ks[64 * 40];      // K tile,  row stride 40
    __shared__ __align__(16) short Vt[32 * 72];      // V^T tile, row stride 72
    __shared__ __align__(16) short Ps[4][32 * 72];   // per-wave P tile

    // Q fragments: row = lm, k(dh) = lg*8 + j  (scale folded in)
    bf16x8 qa[2];
    #pragma unroll
    for (int qt = 0; qt < 2; ++qt) {
        const float* Qp = QKV + gb + (size_t)(q0 + qt * 16 + lm) * 768 + h * 32 + lg * 8;
        float4 f0 = *(const float4*)Qp;
        float4 f1 = *(const float4*)(Qp + 4);
        bf16x8 qv;
        qv[0] = f2bf(f0.x * rscale); qv[1] = f2bf(f0.y * rscale);
        qv[2] = f2bf(f0.z * rscale); qv[3] = f2bf(f0.w * rscale);
        qv[4] = f2bf(f1.x * rscale); qv[5] = f2bf(f1.y * rscale);
        qv[6] = f2bf(f1.z * rscale); qv[7] = f2bf(f1.w * rscale);
        qa[qt] = qv;
    }

    f32x4 acc[2][2];
    #pragma unroll
    for (int qt = 0; qt < 2; ++qt)
        #pragma unroll
        for (int hf = 0; hf < 2; ++hf)
            acc[qt][hf] = (f32x4){0.f, 0.f, 0.f, 0.f};
    float lsum[2][4] = {};

    const int srow = t >> 2;        // staging: key row 0..63
    const int sq = (t & 3) * 8;     // staging: dh offset 0,8,16,24

    for (int kt = 0; kt < 16; ++kt) {
        // ---- stage K tile and V^T tile (f32 -> bf16) ----
        const float* Kp = QKV + gb + (size_t)(kt * 64 + srow) * 768 + 256 + h * 32 + sq;
        const float* Vp = QKV + gb + (size_t)(kt * 64 + srow) * 768 + 512 + h * 32 + sq;
        float4 k0 = *(const float4*)Kp;
        float4 k1 = *(const float4*)(Kp + 4);
        float4 v0 = *(const float4*)Vp;
        float4 v1 = *(const float4*)(Vp + 4);
        bf16x8 kv;
        kv[0] = f2bf(k0.x); kv[1] = f2bf(k0.y); kv[2] = f2bf(k0.z); kv[3] = f2bf(k0.w);
        kv[4] = f2bf(k1.x); kv[5] = f2bf(k1.y); kv[6] = f2bf(k1.z); kv[7] = f2bf(k1.w);
        *(bf16x8*)&Ks[srow * 40 + sq] = kv;
        short vb[8] = { f2bf(v0.x), f2bf(v0.y), f2bf(v0.z), f2bf(v0.w),
                        f2bf(v1.x), f2bf(v1.y), f2bf(v1.z), f2bf(v1.w) };
        #pragma unroll
        for (int j = 0; j < 8; ++j) Vt[(sq + j) * 72 + srow] = vb[j];
        __syncthreads();

        // ---- QK^T (full dh=32 per mfma) + exp + P -> LDS ----
        #pragma unroll
        for (int qt = 0; qt < 2; ++qt) {
            #pragma unroll
            for (int s = 0; s < 4; ++s) {
                bf16x8 kf = *(const bf16x8*)&Ks[(s * 16 + lm) * 40 + lg * 8];
                f32x4 c = (f32x4){0.f, 0.f, 0.f, 0.f};
                c = __builtin_amdgcn_mfma_f32_16x16x32_bf16(qa[qt], kf, c, 0, 0, 0);
                #pragma unroll
                for (int r = 0; r < 4; ++r) {
                    float p = __expf(c[r]);
                    lsum[qt][r] += p;
                    Ps[w][(qt * 16 + lg * 4 + r) * 72 + s * 16 + lm] = f2bf(p);
                }
            }
        }

        // ---- PV: O[32q][32dh] += P[32q][64k] @ V[64k][32dh] ----
        bf16x8 vf[2][2];
        #pragma unroll
        for (int hf = 0; hf < 2; ++hf)
            #pragma unroll
            for (int g = 0; g < 2; ++g)
                vf[hf][g] = *(const bf16x8*)&Vt[(hf * 16 + lm) * 72 + g * 32 + lg * 8];
        #pragma unroll
        for (int qt = 0; qt < 2; ++qt) {
            #pragma unroll
            for (int g = 0; g < 2; ++g) {
                bf16x8 pf = *(const bf16x8*)&Ps[w][(qt * 16 + lm) * 72 + g * 32 + lg * 8];
                #pragma unroll
                for (int hf = 0; hf < 2; ++hf)
                    acc[qt][hf] = __builtin_amdgcn_mfma_f32_16x16x32_bf16(
                        pf, vf[hf][g], acc[qt][hf], 0, 0, 0);
            }
        }
        __syncthreads();
    }

    // ---- denominator reduce over the 16 col-lanes; write O ----
    #pragma unroll
    for (int qt = 0; qt < 2; ++qt) {
        #pragma unroll
        for (int r = 0; r < 4; ++r) {
            float v = lsum[qt][r];
            for (int off = 1; off < 16; off <<= 1) v += __shfl_xor(v, off);
            float inv = 1.0f / v;
            int qrow = q0 + qt * 16 + lg * 4 + r;
            float* Op = O + ((size_t)b * PG + qrow) * D + h * 32;
            Op[lm]      = acc[qt][0][r] * inv;
            Op[16 + lm] = acc[qt][1][r] * inv;
        }
    }
}

// ---------------------------------------------------------------------------
// BatchNorm stats / apply
// ---------------------------------------------------------------------------
__global__ __launch_bounds__(256) void bn_stats(
    const float* __restrict__ X, float* __restrict__ st)
{
    const int c = threadIdx.x;
    const size_t r0 = (size_t)blockIdx.x * 64;
    float s = 0.f, q = 0.f;
    for (int r = 0; r < 64; ++r) {
        float v = X[(r0 + r) * D + c];
        s += v; q = fmaf(v, v, q);
    }
    atomicAdd(&st[c], s);
    atomicAdd(&st[D + c], q);
}

__global__ __launch_bounds__(256) void bn_combine(
    const float* __restrict__ A, const float* __restrict__ Bp,
    const float* __restrict__ gl, const float* __restrict__ bl,
    const float* __restrict__ ga, const float* __restrict__ ba,
    const float* __restrict__ st, float* __restrict__ H, int n)
{
    const float invN = 1.0f / (float)n;
    size_t i = (size_t)blockIdx.x * 256 + threadIdx.x;
    int c0 = (int)((i & 63) << 2);
    float4 a = ((const float4*)A)[i];
    float4 bb = ((const float4*)Bp)[i];
    float av[4] = {a.x, a.y, a.z, a.w}, bv[4] = {bb.x, bb.y, bb.z, bb.w}, r[4];
    #pragma unroll
    for (int j = 0; j < 4; ++j) {
        int c = c0 + j;
        float m1 = st[c] * invN;
        float v1 = fmaxf(st[D + c] * invN - m1 * m1, 0.f);
        float m2 = st[2*D + c] * invN;
        float v2 = fmaxf(st[3*D + c] * invN - m2 * m2, 0.f);
        float y1 = gl[c] * (av[j] - m1) * rsqrtf(v1 + 1e-5f) + bl[c];
        float y2 = ga[c] * (bv[j] - m2) * rsqrtf(v2 + 1e-5f) + ba[c];
        r[j] = y1 + y2;
    }
    float4 o; o.x = r[0]; o.y = r[1]; o.z = r[2]; o.w = r[3];
    ((float4*)H)[i] = o;
}

__global__ __launch_bounds__(256) void bn_apply(
    const float* __restrict__ X, const float* __restrict__ g,
    const float* __restrict__ bb, const float* __restrict__ st,
    float* __restrict__ out, int n)
{
    const float invN = 1.0f / (float)n;
    size_t i = (size_t)blockIdx.x * 256 + threadIdx.x;
    int c0 = (int)((i & 63) << 2);
    float4 xv = ((const float4*)X)[i];
    float x4[4] = {xv.x, xv.y, xv.z, xv.w}, r[4];
    #pragma unroll
    for (int j = 0; j < 4; ++j) {
        int c = c0 + j;
        float m = st[c] * invN;
        float v = fmaxf(st[D + c] * invN - m * m, 0.f);
        r[j] = g[c] * (x4[j] - m) * rsqrtf(v + 1e-5f) + bb[c];
    }
    float4 o; o.x = r[0]; o.y = r[1]; o.z = r[2]; o.w = r[3];
    ((float4*)out)[i] = o;
}

// ---------------------------------------------------------------------------
extern "C" void kernel_launch(void* const* d_in, const int* in_sizes, int n_in,
                              void* d_out, int out_size, void* d_ws, size_t ws_size,
                              hipStream_t stream)
{
    const float* x    = (const float*)d_in[0];
    const int*   ei   = (const int*)d_in[1];
    const float* ea   = (const float*)d_in[2];
    const float* gw1  = (const float*)d_in[3];
    const float* gb1  = (const float*)d_in[4];
    const float* gw2  = (const float*)d_in[5];
    const float* gb2  = (const float*)d_in[6];
    const float* inw  = (const float*)d_in[7];
    const float* inb  = (const float*)d_in[8];
    const float* outw = (const float*)d_in[9];
    const float* outb = (const float*)d_in[10];
    const float* g1l  = (const float*)d_in[11];
    const float* b1l  = (const float*)d_in[12];
    const float* g1a  = (const float*)d_in[13];
    const float* b1a  = (const float*)d_in[14];
    const float* fw1  = (const float*)d_in[15];
    const float* fb1  = (const float*)d_in[16];
    const float* fw2  = (const float*)d_in[17];
    const float* fb2  = (const float*)d_in[18];
    const float* g2   = (const float*)d_in[19];
    const float* b2   = (const float*)d_in[20];
    float* out = (float*)d_out;

    const int N = in_sizes[0] / D;   // 32768
    const int E = in_sizes[1] / 2;   // 262144
    const size_t ND = (size_t)N * D;

    float* U0 = (float*)d_ws;
    float* U1 = U0 + ND;
    float* U2 = U0 + 2 * ND;
    float* U3 = U0 + 3 * ND;
    float* U4 = U0 + 4 * ND;
    float* st = U0 + 5 * ND;

    int* cnt    = (int*)(st + 1536);
    int* excl   = cnt + N;
    int* rowptr = excl + N;
    int* ofs    = rowptr + N;
    int* bsum   = ofs + N;
    int* eord   = bsum + 256;
    int* esrc   = eord + E;

    const int GR = N / 128;
    const int EB = (E + 255) / 256;

    // ---- CSR build ----
    hipMemsetAsync(cnt, 0, (size_t)N * sizeof(int), stream);
    hipMemsetAsync(st, 0, 1536 * sizeof(float), stream);
    hist_kernel<<<EB, 256, 0, stream>>>(ei + E, cnt, E);
    scan_block<<<N / 256, 256, 0, stream>>>(cnt, excl, bsum);
    scan_bsum<<<1, 128, 0, stream>>>(bsum);
    scan_add<<<N / 256, 256, 0, stream>>>(excl, bsum, rowptr, ofs);
    scatter_kernel<<<EB, 256, 0, stream>>>(ei, ei + E, ofs, eord, esrc, E);

    // ---- local branch ----
    csr_aggr<<<(N * 64) / 256, 256, 0, stream>>>(x, ea, rowptr, cnt, eord, esrc, U4);
    gemm_xwt<true , false><<<dim3(D/64, GR), 256, 0, stream>>>(U4, gw1, gb1, nullptr, U1, D, D);
    gemm_xwt<false, true ><<<dim3(D/64, GR), 256, 0, stream>>>(U1, gw2, gb2, x, U0, D, D);

    // ---- global branch: QKV -> MFMA attention -> out-proj ----
    gemm_xwt<false, false><<<dim3(768/64, GR), 256, 0, stream>>>(x, inw, inb, nullptr, U1, D, 768);
    attn_mfma<<<(N / PG) * 8 * 8, 256, 0, stream>>>(U1, U4);
    gemm_xwt<false, true ><<<dim3(D/64, GR), 256, 0, stream>>>(U4, outw, outb, x, U1, D, D);

    // ---- BN both branches, combine ----
    bn_stats<<<N/64, 256, 0, stream>>>(U0, st);
    bn_stats<<<N/64, 256, 0, stream>>>(U1, st + 512);
    bn_combine<<<(unsigned)(ND / 4 / 256), 256, 0, stream>>>(U0, U1, g1l, b1l, g1a, b1a, st, U2, N);

    // ---- FF + final BN ----
    gemm_xwt<true , false><<<dim3(512/64, GR), 256, 0, stream>>>(U2, fw1, fb1, nullptr, U3, D, 512);
    gemm_xwt<false, true ><<<dim3(D/64, GR), 256, 0, stream>>>(U3, fw2, fb2, U2, U0, 512, D);
    bn_stats<<<N/64, 256, 0, stream>>>(U0, st + 1024);
    bn_apply<<<(unsigned)(ND / 4 / 256), 256, 0, stream>>>(U0, g2, b2, st + 1024, out, N);
}

// Round 4
// 454.310 us; speedup vs baseline: 5.0802x; 2.0866x over previous
//
#include <hip/hip_runtime.h>
#include <hip/hip_bf16.h>

constexpr int D = 256;   // dim_h
constexpr int PG = 1024; // nodes per graph

typedef __attribute__((ext_vector_type(8))) short bf16x8;  // 8 bf16 in 4 VGPRs
typedef __attribute__((ext_vector_type(4))) float f32x4;

__device__ inline short f2bf(float f) {
    __hip_bfloat16 h = __float2bfloat16(f);
    return *reinterpret_cast<short*>(&h);
}

// ===========================================================================
// f32 -> bf16 converters
// ===========================================================================
__global__ __launch_bounds__(256) void cvt_bf16(
    const float* __restrict__ X, short* __restrict__ Y)
{
    int i = blockIdx.x * 256 + threadIdx.x;
    float4 a = ((const float4*)X)[i * 2];
    float4 b = ((const float4*)X)[i * 2 + 1];
    bf16x8 v;
    v[0] = f2bf(a.x); v[1] = f2bf(a.y); v[2] = f2bf(a.z); v[3] = f2bf(a.w);
    v[4] = f2bf(b.x); v[5] = f2bf(b.y); v[6] = f2bf(b.z); v[7] = f2bf(b.w);
    ((bf16x8*)Y)[i] = v;
}

// all six weight matrices fused; element/8 prefixes hardcoded for D=256
__global__ __launch_bounds__(256) void cvt_weights(
    const float* __restrict__ w1, const float* __restrict__ w2,
    const float* __restrict__ w3, const float* __restrict__ w4,
    const float* __restrict__ w5, const float* __restrict__ w6,
    short* __restrict__ out)
{
    int i = blockIdx.x * 256 + threadIdx.x;   // [0, 81920)
    const float* src; int base;
    if (i < 16384)      { if (i < 8192) { src = w1; base = 0; }
                          else          { src = w2; base = 8192; } }
    else if (i < 40960) { src = w3; base = 16384; }
    else if (i < 49152) { src = w4; base = 40960; }
    else if (i < 65536) { src = w5; base = 49152; }
    else                { src = w6; base = 65536; }
    int k = i - base;
    float4 a = ((const float4*)src)[k * 2];
    float4 b = ((const float4*)src)[k * 2 + 1];
    bf16x8 v;
    v[0] = f2bf(a.x); v[1] = f2bf(a.y); v[2] = f2bf(a.z); v[3] = f2bf(a.w);
    v[4] = f2bf(b.x); v[5] = f2bf(b.y); v[6] = f2bf(b.z); v[7] = f2bf(b.w);
    ((bf16x8*)out)[i] = v;
}

// ===========================================================================
// CSR build: histogram -> 2-level exclusive scan -> scatter
// ===========================================================================
__global__ __launch_bounds__(256) void hist_kernel(
    const int* __restrict__ dst, int* __restrict__ cnt, int E)
{
    int e = blockIdx.x * 256 + threadIdx.x;
    if (e < E) atomicAdd(&cnt[dst[e]], 1);
}

__global__ __launch_bounds__(256) void scan_block(
    const int* __restrict__ cnt, int* __restrict__ excl, int* __restrict__ bsum)
{
    __shared__ int sm[256];
    const int t = threadIdx.x;
    const int i = blockIdx.x * 256 + t;
    int v = cnt[i];
    sm[t] = v;
    __syncthreads();
    #pragma unroll
    for (int o = 1; o < 256; o <<= 1) {
        int u = (t >= o) ? sm[t - o] : 0;
        __syncthreads();
        sm[t] += u;
        __syncthreads();
    }
    excl[i] = sm[t] - v;
    if (t == 255) bsum[blockIdx.x] = sm[255];
}

__global__ __launch_bounds__(128) void scan_bsum(int* __restrict__ bsum)
{
    __shared__ int sm[128];
    const int t = threadIdx.x;
    int v = bsum[t];
    sm[t] = v;
    __syncthreads();
    #pragma unroll
    for (int o = 1; o < 128; o <<= 1) {
        int u = (t >= o) ? sm[t - o] : 0;
        __syncthreads();
        sm[t] += u;
        __syncthreads();
    }
    bsum[t] = sm[t] - v;
}

__global__ __launch_bounds__(256) void scan_add(
    const int* __restrict__ excl, const int* __restrict__ bsum,
    int* __restrict__ rowptr, int* __restrict__ ofs)
{
    int i = blockIdx.x * 256 + threadIdx.x;
    int r = excl[i] + bsum[blockIdx.x];
    rowptr[i] = r;
    ofs[i] = r;
}

__global__ __launch_bounds__(256) void scatter_kernel(
    const int* __restrict__ src, const int* __restrict__ dst,
    int* __restrict__ ofs, int* __restrict__ eord, int* __restrict__ esrc, int E)
{
    int e = blockIdx.x * 256 + threadIdx.x;
    if (e >= E) return;
    int d = dst[e];
    int pos = atomicAdd(&ofs[d], 1);
    eord[pos] = e;
    esrc[pos] = src[e];
}

// ===========================================================================
// CSR aggregation -> bf16 Z. One wave per dst node.
// ===========================================================================
__global__ __launch_bounds__(256) void csr_aggr(
    const float* __restrict__ x, const float* __restrict__ ea,
    const int* __restrict__ rowptr, const int* __restrict__ cnt,
    const int* __restrict__ eord, const int* __restrict__ esrc,
    short* __restrict__ z)
{
    int gid = blockIdx.x * 256 + threadIdx.x;
    int node = gid >> 6;
    int c = (gid & 63) << 2;
    int start = rowptr[node];
    int deg = cnt[node];
    float4 acc = *(const float4*)(x + (size_t)node * D + c);
    for (int i = 0; i < deg; ++i) {
        int e = eord[start + i];
        int s = esrc[start + i];
        float4 xa = *(const float4*)(x + (size_t)s * D + c);
        float4 av = *(const float4*)(ea + (size_t)e * D + c);
        acc.x += fmaxf(xa.x + av.x, 0.f);
        acc.y += fmaxf(xa.y + av.y, 0.f);
        acc.z += fmaxf(xa.z + av.z, 0.f);
        acc.w += fmaxf(xa.w + av.w, 0.f);
    }
    short4 r;
    r.x = f2bf(acc.x); r.y = f2bf(acc.y); r.z = f2bf(acc.z); r.w = f2bf(acc.w);
    *(short4*)(z + (size_t)node * D + c) = r;
}

// ===========================================================================
// MFMA bf16 GEMM: Y = act(X @ W^T + bias) (+ addsrc), X:[R,K] W:[M,K] bf16.
// Tile 128x128, BK=64, 4 waves (each 64x64 = 4x4 16x16 frags).
// LDS pad stride 72 shorts (144B) -> 2-way conflicts only. XCD-chunk swizzle.
// ===========================================================================
template<bool RELU, bool ADD, bool OUTB>
__global__ __launch_bounds__(256) void gemm_mfma(
    const short* __restrict__ X, const short* __restrict__ W,
    const float* __restrict__ bias, const float* __restrict__ addsrc,
    float* __restrict__ Yf, short* __restrict__ Yb, int K, int M)
{
    __shared__ __align__(16) short Xs[128 * 72];
    __shared__ __align__(16) short Ws[128 * 72];

    const int nbx = gridDim.x;
    const int nwg = nbx * gridDim.y;
    const int bid = blockIdx.y * nbx + blockIdx.x;
    const int cpx = nwg >> 3;                     // all grids are %8 == 0
    const int wg  = (bid & 7) * cpx + (bid >> 3);
    const int r0 = (wg / nbx) * 128;
    const int c0 = (wg % nbx) * 128;

    const int t = threadIdx.x, w = t >> 6, l = t & 63;
    const int wr = w >> 1, wc = w & 1, lg = l >> 4, lm = l & 15;
    const int srow = t >> 3;            // staging row 0..31
    const int scol = (t & 7) * 8;       // staging col 0..56

    f32x4 acc[4][4];
    #pragma unroll
    for (int i = 0; i < 4; ++i)
        #pragma unroll
        for (int j = 0; j < 4; ++j)
            acc[i][j] = (f32x4){0.f, 0.f, 0.f, 0.f};

    for (int k0 = 0; k0 < K; k0 += 64) {
        __syncthreads();
        #pragma unroll
        for (int it = 0; it < 4; ++it) {
            int r = it * 32 + srow;
            bf16x8 xv = *(const bf16x8*)(X + (size_t)(r0 + r) * K + k0 + scol);
            bf16x8 wv = *(const bf16x8*)(W + (size_t)(c0 + r) * K + k0 + scol);
            *(bf16x8*)&Xs[r * 72 + scol] = xv;
            *(bf16x8*)&Ws[r * 72 + scol] = wv;
        }
        __syncthreads();

        bf16x8 af[4][2], bfr[4][2];
        #pragma unroll
        for (int i = 0; i < 4; ++i)
            #pragma unroll
            for (int ks = 0; ks < 2; ++ks) {
                af[i][ks]  = *(const bf16x8*)&Xs[(wr*64 + i*16 + lm)*72 + ks*32 + lg*8];
                bfr[i][ks] = *(const bf16x8*)&Ws[(wc*64 + i*16 + lm)*72 + ks*32 + lg*8];
            }
        #pragma unroll
        for (int i = 0; i < 4; ++i)
            #pragma unroll
            for (int j = 0; j < 4; ++j) {
                acc[i][j] = __builtin_amdgcn_mfma_f32_16x16x32_bf16(af[i][0], bfr[j][0], acc[i][j], 0, 0, 0);
                acc[i][j] = __builtin_amdgcn_mfma_f32_16x16x32_bf16(af[i][1], bfr[j][1], acc[i][j], 0, 0, 0);
            }
    }

    #pragma unroll
    for (int j = 0; j < 4; ++j) {
        int col = c0 + wc*64 + j*16 + lm;
        float bj = bias[col];
        #pragma unroll
        for (int i = 0; i < 4; ++i) {
            #pragma unroll
            for (int r = 0; r < 4; ++r) {
                int row = r0 + wr*64 + i*16 + lg*4 + r;
                size_t off = (size_t)row * M + col;
                float v = acc[i][j][r] + bj;
                if (RELU) v = fmaxf(v, 0.f);
                if (ADD)  v += addsrc[off];
                if (OUTB) Yb[off] = f2bf(v);
                else      Yf[off] = v;
            }
        }
    }
}

// ===========================================================================
// MFMA bf16 attention (bf16 QKV in, bf16 O out). Layouts as round-3 (verified).
// ===========================================================================
__global__ __launch_bounds__(256) void attn_mfma(
    const short* __restrict__ QKV, short* __restrict__ O)
{
    const int bh = blockIdx.x & 255;
    const int qblk = blockIdx.x >> 8;
    const int b = bh >> 3, h = bh & 7;
    const int t = threadIdx.x, w = t >> 6, l = t & 63;
    const int lg = l >> 4, lm = l & 15;
    const size_t gb = (size_t)b * PG * 768;
    const int q0 = qblk * 128 + w * 32;
    const float rscale = 0.17677669529663687f;  // 1/sqrt(32)

    __shared__ __align__(16) short Ks[64 * 40];
    __shared__ __align__(16) short Vt[32 * 72];
    __shared__ __align__(16) short Ps[4][32 * 72];

    bf16x8 qa[2];
    #pragma unroll
    for (int qt = 0; qt < 2; ++qt)
        qa[qt] = *(const bf16x8*)(QKV + gb + (size_t)(q0 + qt*16 + lm) * 768 + h*32 + lg*8);

    f32x4 acc[2][2];
    #pragma unroll
    for (int qt = 0; qt < 2; ++qt)
        #pragma unroll
        for (int hf = 0; hf < 2; ++hf)
            acc[qt][hf] = (f32x4){0.f, 0.f, 0.f, 0.f};
    float lsum[2][4] = {};

    const int srow = t >> 2;
    const int sq = (t & 3) * 8;

    for (int kt = 0; kt < 16; ++kt) {
        bf16x8 kv = *(const bf16x8*)(QKV + gb + (size_t)(kt*64 + srow) * 768 + 256 + h*32 + sq);
        bf16x8 vv = *(const bf16x8*)(QKV + gb + (size_t)(kt*64 + srow) * 768 + 512 + h*32 + sq);
        *(bf16x8*)&Ks[srow * 40 + sq] = kv;
        #pragma unroll
        for (int j = 0; j < 8; ++j) Vt[(sq + j) * 72 + srow] = vv[j];
        __syncthreads();

        #pragma unroll
        for (int qt = 0; qt < 2; ++qt) {
            #pragma unroll
            for (int s = 0; s < 4; ++s) {
                bf16x8 kf = *(const bf16x8*)&Ks[(s*16 + lm) * 40 + lg*8];
                f32x4 c = (f32x4){0.f, 0.f, 0.f, 0.f};
                c = __builtin_amdgcn_mfma_f32_16x16x32_bf16(qa[qt], kf, c, 0, 0, 0);
                #pragma unroll
                for (int r = 0; r < 4; ++r) {
                    float p = __expf(c[r] * rscale);
                    lsum[qt][r] += p;
                    Ps[w][(qt*16 + lg*4 + r) * 72 + s*16 + lm] = f2bf(p);
                }
            }
        }

        bf16x8 vf[2][2];
        #pragma unroll
        for (int hf = 0; hf < 2; ++hf)
            #pragma unroll
            for (int g = 0; g < 2; ++g)
                vf[hf][g] = *(const bf16x8*)&Vt[(hf*16 + lm) * 72 + g*32 + lg*8];
        #pragma unroll
        for (int qt = 0; qt < 2; ++qt) {
            #pragma unroll
            for (int g = 0; g < 2; ++g) {
                bf16x8 pf = *(const bf16x8*)&Ps[w][(qt*16 + lm) * 72 + g*32 + lg*8];
                #pragma unroll
                for (int hf = 0; hf < 2; ++hf)
                    acc[qt][hf] = __builtin_amdgcn_mfma_f32_16x16x32_bf16(
                        pf, vf[hf][g], acc[qt][hf], 0, 0, 0);
            }
        }
        __syncthreads();
    }

    #pragma unroll
    for (int qt = 0; qt < 2; ++qt) {
        #pragma unroll
        for (int r = 0; r < 4; ++r) {
            float v = lsum[qt][r];
            for (int off = 1; off < 16; off <<= 1) v += __shfl_xor(v, off);
            float inv = 1.0f / v;
            int qrow = q0 + qt*16 + lg*4 + r;
            short* Op = O + ((size_t)b * PG + qrow) * D + h * 32;
            Op[lm]      = f2bf(acc[qt][0][r] * inv);
            Op[16 + lm] = f2bf(acc[qt][1][r] * inv);
        }
    }
}

// ---------------------------------------------------------------------------
// BatchNorm stats / combine / apply
// ---------------------------------------------------------------------------
__global__ __launch_bounds__(256) void bn_stats(
    const float* __restrict__ X, float* __restrict__ st)
{
    const int c = threadIdx.x;
    const size_t r0 = (size_t)blockIdx.x * 64;
    float s = 0.f, q = 0.f;
    for (int r = 0; r < 64; ++r) {
        float v = X[(r0 + r) * D + c];
        s += v; q = fmaf(v, v, q);
    }
    atomicAdd(&st[c], s);
    atomicAdd(&st[D + c], q);
}

__global__ __launch_bounds__(256) void bn_combine(
    const float* __restrict__ A, const float* __restrict__ Bp,
    const float* __restrict__ gl, const float* __restrict__ bl,
    const float* __restrict__ ga, const float* __restrict__ ba,
    const float* __restrict__ st, float* __restrict__ H,
    short* __restrict__ Hb, int n)
{
    const float invN = 1.0f / (float)n;
    size_t i = (size_t)blockIdx.x * 256 + threadIdx.x;
    int c0 = (int)((i & 63) << 2);
    float4 a = ((const float4*)A)[i];
    float4 bb = ((const float4*)Bp)[i];
    float av[4] = {a.x, a.y, a.z, a.w}, bv[4] = {bb.x, bb.y, bb.z, bb.w}, r[4];
    #pragma unroll
    for (int j = 0; j < 4; ++j) {
        int c = c0 + j;
        float m1 = st[c] * invN;
        float v1 = fmaxf(st[D + c] * invN - m1 * m1, 0.f);
        float m2 = st[2*D + c] * invN;
        float v2 = fmaxf(st[3*D + c] * invN - m2 * m2, 0.f);
        float y1 = gl[c] * (av[j] - m1) * rsqrtf(v1 + 1e-5f) + bl[c];
        float y2 = ga[c] * (bv[j] - m2) * rsqrtf(v2 + 1e-5f) + ba[c];
        r[j] = y1 + y2;
    }
    float4 o; o.x = r[0]; o.y = r[1]; o.z = r[2]; o.w = r[3];
    ((float4*)H)[i] = o;
    short4 hb;
    hb.x = f2bf(r[0]); hb.y = f2bf(r[1]); hb.z = f2bf(r[2]); hb.w = f2bf(r[3]);
    ((short4*)Hb)[i] = hb;
}

__global__ __launch_bounds__(256) void bn_apply(
    const float* __restrict__ X, const float* __restrict__ g,
    const float* __restrict__ bb, const float* __restrict__ st,
    float* __restrict__ out, int n)
{
    const float invN = 1.0f / (float)n;
    size_t i = (size_t)blockIdx.x * 256 + threadIdx.x;
    int c0 = (int)((i & 63) << 2);
    float4 xv = ((const float4*)X)[i];
    float x4[4] = {xv.x, xv.y, xv.z, xv.w}, r[4];
    #pragma unroll
    for (int j = 0; j < 4; ++j) {
        int c = c0 + j;
        float m = st[c] * invN;
        float v = fmaxf(st[D + c] * invN - m * m, 0.f);
        r[j] = g[c] * (x4[j] - m) * rsqrtf(v + 1e-5f) + bb[c];
    }
    float4 o; o.x = r[0]; o.y = r[1]; o.z = r[2]; o.w = r[3];
    ((float4*)out)[i] = o;
}

// ---------------------------------------------------------------------------
extern "C" void kernel_launch(void* const* d_in, const int* in_sizes, int n_in,
                              void* d_out, int out_size, void* d_ws, size_t ws_size,
                              hipStream_t stream)
{
    const float* x    = (const float*)d_in[0];
    const int*   ei   = (const int*)d_in[1];
    const float* ea   = (const float*)d_in[2];
    const float* gw1  = (const float*)d_in[3];
    const float* gb1  = (const float*)d_in[4];
    const float* gw2  = (const float*)d_in[5];
    const float* gb2  = (const float*)d_in[6];
    const float* inw  = (const float*)d_in[7];
    const float* inb  = (const float*)d_in[8];
    const float* outw = (const float*)d_in[9];
    const float* outb = (const float*)d_in[10];
    const float* g1l  = (const float*)d_in[11];
    const float* b1l  = (const float*)d_in[12];
    const float* g1a  = (const float*)d_in[13];
    const float* b1a  = (const float*)d_in[14];
    const float* fw1  = (const float*)d_in[15];
    const float* fb1  = (const float*)d_in[16];
    const float* fw2  = (const float*)d_in[17];
    const float* fb2  = (const float*)d_in[18];
    const float* g2   = (const float*)d_in[19];
    const float* b2   = (const float*)d_in[20];
    float* out = (float*)d_out;

    const int N = in_sizes[0] / D;   // 32768
    const int E = in_sizes[1] / 2;   // 262144
    const size_t ND = (size_t)N * D;

    // ---- workspace layout ----
    float* F0 = (float*)d_ws;        // HLpre -> OUTpre (f32)
    float* F1 = F0 + ND;             // HApre (f32)
    float* F2 = F0 + 2 * ND;         // Hc (f32)
    short* Bp = (short*)(F0 + 3 * ND);  // 4*ND bf16 pool
    short* Zb   = Bp;                // csr out        (phase A)
    short* T1b  = Bp + ND;           // gemm1 out      (phase A)
    short* xb   = Bp + 3 * ND;       // x bf16         (until qkv done)
    short* QKVb = Bp;                // 3*ND           (phase B, after gemm2)
    short* Ob   = Bp + 3 * ND;       // attn out       (reuse xb)
    short* HcB  = Bp;                // bn_combine bf16 out (phase C)
    short* FFHb = Bp + ND;           // ff1 out, 2*ND  (phase C)
    short* Wb   = Bp + 4 * ND;       // 655360 shorts of bf16 weights
    short* gw1b = Wb, *gw2b = Wb + 65536, *inwb = Wb + 131072;
    short* outwb = Wb + 327680, *fw1b = Wb + 393216, *fw2b = Wb + 524288;
    float* st = (float*)(Wb + 655360);
    int* cnt    = (int*)(st + 1536);
    int* excl   = cnt + N;
    int* rowptr = excl + N;
    int* ofs    = rowptr + N;
    int* bsum   = ofs + N;
    int* eord   = bsum + 256;
    int* esrc   = eord + E;

    const int GR = N / 128;          // 256 row-blocks
    const int EB = (E + 255) / 256;

    // ---- converts ----
    cvt_bf16<<<(unsigned)(ND / 8 / 256), 256, 0, stream>>>(x, xb);
    cvt_weights<<<320, 256, 0, stream>>>(gw1, gw2, inw, outw, fw1, fw2, Wb);

    // ---- CSR build ----
    hipMemsetAsync(cnt, 0, (size_t)N * sizeof(int), stream);
    hipMemsetAsync(st, 0, 1536 * sizeof(float), stream);
    hist_kernel<<<EB, 256, 0, stream>>>(ei + E, cnt, E);
    scan_block<<<N / 256, 256, 0, stream>>>(cnt, excl, bsum);
    scan_bsum<<<1, 128, 0, stream>>>(bsum);
    scan_add<<<N / 256, 256, 0, stream>>>(excl, bsum, rowptr, ofs);
    scatter_kernel<<<EB, 256, 0, stream>>>(ei, ei + E, ofs, eord, esrc, E);

    // ---- local branch ----
    csr_aggr<<<(N * 64) / 256, 256, 0, stream>>>(x, ea, rowptr, cnt, eord, esrc, Zb);
    gemm_mfma<true , false, true ><<<dim3(2, GR), 256, 0, stream>>>(Zb, gw1b, gb1, nullptr, nullptr, T1b, D, D);
    gemm_mfma<false, true , false><<<dim3(2, GR), 256, 0, stream>>>(T1b, gw2b, gb2, x, F0, nullptr, D, D);

    // ---- global branch ----
    gemm_mfma<false, false, true ><<<dim3(6, GR), 256, 0, stream>>>(xb, inwb, inb, nullptr, nullptr, QKVb, D, 768);
    attn_mfma<<<(N / PG) * 8 * 8, 256, 0, stream>>>(QKVb, Ob);
    gemm_mfma<false, true , false><<<dim3(2, GR), 256, 0, stream>>>(Ob, outwb, outb, x, F1, nullptr, D, D);

    // ---- BN both branches, combine ----
    bn_stats<<<N/64, 256, 0, stream>>>(F0, st);
    bn_stats<<<N/64, 256, 0, stream>>>(F1, st + 512);
    bn_combine<<<(unsigned)(ND / 4 / 256), 256, 0, stream>>>(F0, F1, g1l, b1l, g1a, b1a, st, F2, HcB, N);

    // ---- FF + final BN ----
    gemm_mfma<true , false, true ><<<dim3(4, GR), 256, 0, stream>>>(HcB, fw1b, fb1, nullptr, nullptr, FFHb, D, 512);
    gemm_mfma<false, true , false><<<dim3(2, GR), 256, 0, stream>>>(FFHb, fw2b, fb2, F2, F0, nullptr, 512, D);
    bn_stats<<<N/64, 256, 0, stream>>>(F0, st + 1024);
    bn_apply<<<(unsigned)(ND / 4 / 256), 256, 0, stream>>>(F0, g2, b2, st + 1024, out, N);
}